// Round 6
// baseline (5783.917 us; speedup 1.0000x reference)
//
#include <hip/hip_runtime.h>
#include <math.h>

constexpr float LAM = 1.0f;
constexpr int   NIT = 20;
constexpr float TOL = 1e-6f;
constexpr int   TILE = 8192;   // col-tile width (nodes); 2 MB p-window per tile

typedef float f4 __attribute__((ext_vector_type(4)));

// ---------------- scal layout (floats) ----------------
#define S_RSOLD 0
#define S_ALPHA 8
#define S_BETA  16
#define S_FLAG  24        // int alias
#define S_PAP   32        // [8][256] partial slots for p.Ap
#define S_RS    (32+2048) // [8][256] partial slots for r.r
#define SCAL_F  (32+4096)

__device__ __forceinline__ float dot8v(f4 a0, f4 a1, f4 b0, f4 b1){
  return a0[0]*b0[0] + a0[1]*b0[1] + a0[2]*b0[2] + a0[3]*b0[3]
       + a1[0]*b1[0] + a1[1]*b1[1] + a1[2]*b1[2] + a1[3]*b1[3];
}

// zero scal, zero cursor
__global__ void k_setup_nm(float* __restrict__ scal, int* __restrict__ cursor, int Mn){
  int i = blockIdx.x * blockDim.x + threadIdx.x;
  int stride = gridDim.x * blockDim.x;
  for (int j = i; j < SCAL_F; j += stride) scal[j] = 0.f;
  for (int j = i; j < Mn; j += stride) cursor[j] = 0;
}

__global__ void k_deg(const int* __restrict__ src, const int* __restrict__ dst,
                      int* __restrict__ cnt, int E){
  int i = blockIdx.x * blockDim.x + threadIdx.x;
  int stride = gridDim.x * blockDim.x;
  for (int e = i; e < E; e += stride){
    atomicAdd(&cnt[src[e]], 1);
    atomicAdd(&cnt[dst[e]], 1);
  }
}

// exclusive scan (deg+1 per node: slot 0 of each row is the diagonal block)
__global__ void k_scan(int* __restrict__ cnt, int* __restrict__ rowptr,
                       int* __restrict__ cursor, int Mn, int tot){
  __shared__ int sm[1024];
  const int T = 1024;
  int t = threadIdx.x;
  int chunk = (Mn + T - 1) / T;
  int lo = t * chunk, hi = lo + chunk; if (hi > Mn) hi = Mn;
  int s = 0;
  for (int i = lo; i < hi; ++i) s += cnt[i] + 1;
  sm[t] = s;
  __syncthreads();
  for (int o = 1; o < T; o <<= 1){
    int v = (t >= o) ? sm[t - o] : 0;
    __syncthreads();
    sm[t] += v;
    __syncthreads();
  }
  int base = (t == 0) ? 0 : sm[t - 1];
  for (int i = lo; i < hi; ++i){
    int c = cnt[i];
    rowptr[i] = base;
    cursor[i] = base + 1;
    base += c + 1;
  }
  if (t == T - 1) rowptr[Mn] = tot;
}

// fill CSR neighbor slots for partner nodes in [lo,hi) only — called once per
// col-tile so each row's slots end up grouped by ascending col-tile.
__global__ void k_fill_t(const int* __restrict__ src, const int* __restrict__ dst,
                         int* __restrict__ cursor, int* __restrict__ col,
                         int* __restrict__ es, int E, int lo, int hi){
  int i = blockIdx.x * blockDim.x + threadIdx.x;
  int stride = gridDim.x * blockDim.x;
  for (int e = i; e < E; e += stride){
    int s = src[e], t = dst[e];
    if (t >= lo && t < hi){
      int ps = atomicAdd(&cursor[s], 1);
      col[ps] = t; es[ps] = (e << 1);
    }
    if (s >= lo && s < hi){
      int pt = atomicAdd(&cursor[t], 1);
      col[pt] = s; es[pt] = (e << 1) | 1;
    }
  }
}

// wave per node (lane l=(d1,d2)): neighbor slots j in (j0,j1): Bcsr[j] = -LAM*X^T Y.
// Diagonal slot j0: Bcsr[j0] = I + LAM*sum X^T X, col[j0] = v. No atomics.
__global__ void k_buildg(const float* __restrict__ Rs, const float* __restrict__ Rd,
                         const int* __restrict__ rowptr, const int* __restrict__ es,
                         float* __restrict__ Bcsr, int* __restrict__ col, int Mn){
  int g = blockIdx.x * blockDim.x + threadIdx.x;
  int v = g >> 6;
  if (v >= Mn) return;
  int l = g & 63, d1 = l >> 3, d2 = l & 7;
  float Dacc = 0.f;
  int j0 = rowptr[v], j1 = rowptr[v + 1];
  int j = j0 + 1;
  for (; j + 2 <= j1; j += 2){
    int e0 = es[j], e1 = es[j + 1];
    float ra0 = Rs[(size_t)(e0 >> 1) * 64 + l];
    float rb0 = Rd[(size_t)(e0 >> 1) * 64 + l];
    float ra1 = Rs[(size_t)(e1 >> 1) * 64 + l];
    float rb1 = Rd[(size_t)(e1 >> 1) * 64 + l];
    float x0 = (e0 & 1) ? rb0 : ra0, y0 = (e0 & 1) ? ra0 : rb0;
    float x1 = (e1 & 1) ? rb1 : ra1, y1 = (e1 & 1) ? ra1 : rb1;
    float B0 = 0.f, B1 = 0.f;
    #pragma unroll
    for (int a = 0; a < 8; ++a){
      float p0 = __shfl(x0, a * 8 + d1, 64);
      float q0 = __shfl(y0, a * 8 + d2, 64);
      float s0 = __shfl(x0, a * 8 + d2, 64);
      float p1 = __shfl(x1, a * 8 + d1, 64);
      float q1 = __shfl(y1, a * 8 + d2, 64);
      float s1 = __shfl(x1, a * 8 + d2, 64);
      B0 += p0 * q0;  Dacc += p0 * s0;
      B1 += p1 * q1;  Dacc += p1 * s1;
    }
    __builtin_nontemporal_store(-LAM * B0, &Bcsr[(size_t)j * 64 + l]);
    __builtin_nontemporal_store(-LAM * B1, &Bcsr[(size_t)(j + 1) * 64 + l]);
  }
  for (; j < j1; ++j){
    int e0 = es[j];
    float ra = Rs[(size_t)(e0 >> 1) * 64 + l];
    float rb = Rd[(size_t)(e0 >> 1) * 64 + l];
    float x = (e0 & 1) ? rb : ra, y = (e0 & 1) ? ra : rb;
    float B0 = 0.f;
    #pragma unroll
    for (int a = 0; a < 8; ++a){
      float p0 = __shfl(x, a * 8 + d1, 64);
      float q0 = __shfl(y, a * 8 + d2, 64);
      float s0 = __shfl(x, a * 8 + d2, 64);
      B0 += p0 * q0;  Dacc += p0 * s0;
    }
    __builtin_nontemporal_store(-LAM * B0, &Bcsr[(size_t)j * 64 + l]);
  }
  Bcsr[(size_t)j0 * 64 + l] = ((d1 == d2) ? 1.f : 0.f) + LAM * Dacc;
  if (l == 0) col[j0] = v;
}

// wave per node. Two-phase, LDS-staged, double-buffered gather matvec.
// Slots are col-tile-sorted -> p gathers are L2-local (lockstep tile sweep).
__global__ void k_mv(const float* __restrict__ Bcsr, const int* __restrict__ rowptr,
                     const int* __restrict__ col, const float* __restrict__ p,
                     float* __restrict__ out, float* __restrict__ scal, int Mn){
  if (*(const int*)(scal + S_FLAG)) return;
  __shared__ float pbuf[4][2][8][64];
  __shared__ int   cbuf[4][128];
  int g = blockIdx.x * blockDim.x + threadIdx.x;
  int v = g >> 6;
  bool active = (v < Mn);
  int w  = threadIdx.x >> 6;
  int l  = g & 63;
  int hi = l >> 3, lo = l & 7;
  int k8 = lo * 8;          // phase-A segment offset / phase-B B-row offset
  int b8 = hi * 8;          // phase-B batch offset
  int j0 = 0, j1 = 0, rowlen = 0;
  if (active){
    j0 = rowptr[v]; j1 = rowptr[v + 1];
    rowlen = j1 - j0;
    for (int jj = l; jj < rowlen && jj < 128; jj += 64)
      cbuf[w][jj] = col[j0 + jj];
  }
  __syncthreads();
  if (!active) return;

  const int* cb = cbuf[w];
  int nch = (rowlen + 7) >> 3;

  auto gather = [&](int n, f4& g0, f4& g1){
    int jj = n * 8 + hi;
    int c = v;
    if (jj < rowlen) c = (jj < 128) ? cb[jj] : col[j0 + jj];
    const float* pc = p + (size_t)c * 64 + k8;
    g0 = *(const f4*)pc;
    g1 = *(const f4*)(pc + 4);
  };

  {
    f4 u0, u1;
    gather(0, u0, u1);
    float* d0 = &pbuf[w][0][hi][k8];
    *(f4*)d0 = u0; *(f4*)(d0 + 4) = u1;
  }

  float acc = 0.f;
  for (int n = 0; n < nch; ++n){
    int nb = n & 1;
    bool more = (n + 1 < nch);
    f4 g0, g1;
    if (more) gather(n + 1, g0, g1);
    int jb = j0 + n * 8;
    const float* Bbase = Bcsr + (size_t)jb * 64 + k8;
    if (j1 - jb >= 8){
      // full chunk: branch-free, all 16 loads issue back-to-back
      #pragma unroll
      for (int q = 0; q < 8; ++q){
        f4 m0 = __builtin_nontemporal_load((const f4*)(Bbase + q * 64));
        f4 m1 = __builtin_nontemporal_load((const f4*)(Bbase + q * 64 + 4));
        const float* pr = &pbuf[w][nb][q][b8];
        acc += dot8v(m0, m1, *(const f4*)pr, *(const f4*)(pr + 4));
      }
    } else {
      int lim = j1 - jb;
      #pragma unroll
      for (int q = 0; q < 8; ++q){
        if (q < lim){
          f4 m0 = __builtin_nontemporal_load((const f4*)(Bbase + q * 64));
          f4 m1 = __builtin_nontemporal_load((const f4*)(Bbase + q * 64 + 4));
          const float* pr = &pbuf[w][nb][q][b8];
          acc += dot8v(m0, m1, *(const f4*)pr, *(const f4*)(pr + 4));
        }
      }
    }
    if (more){
      float* d1 = &pbuf[w][nb ^ 1][hi][k8];
      *(f4*)d1 = g0; *(f4*)(d1 + 4) = g1;
    }
  }
  out[(size_t)v * 64 + l] = acc;
  // fused p.Ap partial
  float pself = p[(size_t)v * 64 + l];
  float part = pself * acc;
  part += __shfl_xor(part, 1, 64);
  part += __shfl_xor(part, 2, 64);
  part += __shfl_xor(part, 4, 64);
  if (lo == 0)
    atomicAdd(&scal[S_PAP + hi * 256 + (blockIdx.x & 255)], part);
}

// c0 (batch-major) -> node-major buffer
__global__ void k_perm(const float* __restrict__ c0, float* __restrict__ xp, int Mn){
  int i = blockIdx.x * blockDim.x + threadIdx.x;
  int n4 = Mn * 16;
  if (i >= n4) return;
  int v = i >> 4, rem = i & 15, b = rem >> 1, half = rem & 1;
  f4 cv = *(const f4*)(c0 + ((size_t)b * Mn + v) * 8 + half * 4);
  ((f4*)xp)[i] = cv;
}

// r = c0p - Ap; p = r (in place over c0p); x (batch-major, d_out) = c0
__global__ void k_init_nm(float* __restrict__ p, const float* __restrict__ Ap,
                          float* __restrict__ r, float* __restrict__ x_bm,
                          float* __restrict__ scal, int n4tot, int Mn){
  int i = blockIdx.x * blockDim.x + threadIdx.x;
  int l = threadIdx.x & 63;
  float part = 0.f;
  if (i < n4tot){
    f4 cv = ((const f4*)p)[i];
    f4 av = ((const f4*)Ap)[i];
    f4 rv = cv - av;
    ((f4*)r)[i] = rv;
    ((f4*)p)[i] = rv;
    int v = i >> 4, rem = i & 15, b = rem >> 1, half = rem & 1;
    ((f4*)x_bm)[((size_t)b * Mn + v) * 2 + half] = cv;
    part = rv[0]*rv[0] + rv[1]*rv[1] + rv[2]*rv[2] + rv[3]*rv[3];
  }
  part += __shfl_xor(part, 1, 64);
  part += __shfl_xor(part, 16, 64);
  part += __shfl_xor(part, 32, 64);
  if ((l & 49) == 0)
    atomicAdd(&scal[S_RS + ((l >> 1) & 7) * 256 + (blockIdx.x & 255)], part);
}

// once: RSOLD[b] = sum(S_RS); zero both slot arrays
__global__ void k_s0(float* __restrict__ scal){
  __shared__ float sm[256];
  int t = threadIdx.x;
  int b = t >> 5, k0 = t & 31;
  float s = 0.f;
  #pragma unroll
  for (int i = 0; i < 8; ++i) s += scal[S_RS + b * 256 + k0 + i * 32];
  sm[t] = s;
  __syncthreads();
  if (t < 8){
    float tot = 0.f;
    #pragma unroll
    for (int i = 0; i < 32; ++i) tot += sm[t * 32 + i];
    scal[S_RSOLD + t] = tot;
  }
  __syncthreads();
  for (int i = t; i < 4096; i += 256) scal[S_PAP + i] = 0.f;
}

// alpha[b] = rsold[b] / (sum S_PAP slots + eps)
__global__ void k_alpha(float* __restrict__ scal){
  if (*(const int*)(scal + S_FLAG)) return;
  __shared__ float sm[256];
  int t = threadIdx.x;
  int b = t >> 5, k0 = t & 31;
  float s = 0.f;
  #pragma unroll
  for (int i = 0; i < 8; ++i) s += scal[S_PAP + b * 256 + k0 + i * 32];
  sm[t] = s;
  __syncthreads();
  if (t < 8){
    float tot = 0.f;
    #pragma unroll
    for (int i = 0; i < 32; ++i) tot += sm[t * 32 + i];
    scal[S_ALPHA + t] = scal[S_RSOLD + t] / (tot + 1e-12f);
  }
}

// x(batch-major) += a p; r -= a Ap; accumulate rnew.rnew
__global__ void k_upd_nm(float* __restrict__ x_bm, float* __restrict__ r,
                         const float* __restrict__ p, const float* __restrict__ Ap,
                         float* __restrict__ scal, int n4tot, int Mn){
  if (*(const int*)(scal + S_FLAG)) return;
  int i = blockIdx.x * blockDim.x + threadIdx.x;
  int l = threadIdx.x & 63;
  float part = 0.f;
  if (i < n4tot){
    int v = i >> 4, rem = i & 15, b = rem >> 1, half = rem & 1;
    float al = scal[S_ALPHA + b];
    size_t xi = ((size_t)b * Mn + v) * 2 + half;
    f4 pv = ((const f4*)p)[i];
    f4 av = ((const f4*)Ap)[i];
    f4 xv = ((f4*)x_bm)[xi];
    f4 rv = ((f4*)r)[i];
    xv += al * pv;
    rv -= al * av;
    ((f4*)x_bm)[xi] = xv;
    ((f4*)r)[i] = rv;
    part = rv[0]*rv[0] + rv[1]*rv[1] + rv[2]*rv[2] + rv[3]*rv[3];
  }
  part += __shfl_xor(part, 1, 64);
  part += __shfl_xor(part, 16, 64);
  part += __shfl_xor(part, 32, 64);
  if ((l & 49) == 0)
    atomicAdd(&scal[S_RS + ((l >> 1) & 7) * 256 + (blockIdx.x & 255)], part);
}

// rsnew from S_RS; conv flag; BETA/RSOLD; zero slot arrays
__global__ void k_s2(float* __restrict__ scal){
  if (*(const int*)(scal + S_FLAG)) return;
  __shared__ float sm[256];
  __shared__ float rsn[8];
  int t = threadIdx.x;
  int b = t >> 5, k0 = t & 31;
  float s = 0.f;
  #pragma unroll
  for (int i = 0; i < 8; ++i) s += scal[S_RS + b * 256 + k0 + i * 32];
  sm[t] = s;
  __syncthreads();
  if (t < 8){
    float tot = 0.f;
    #pragma unroll
    for (int i = 0; i < 32; ++i) tot += sm[t * 32 + i];
    rsn[t] = tot;
  }
  __syncthreads();
  if (t == 0){
    float ssum = 0.f;
    for (int bb = 0; bb < 8; ++bb) ssum += rsn[bb];
    if (sqrtf(ssum / 8.0f) < TOL){
      *(int*)(scal + S_FLAG) = 1;   // freeze
    } else {
      for (int bb = 0; bb < 8; ++bb){
        scal[S_BETA + bb]  = rsn[bb] / (scal[S_RSOLD + bb] + 1e-12f);
        scal[S_RSOLD + bb] = rsn[bb];
      }
    }
  }
  __syncthreads();
  for (int i = t; i < 4096; i += 256) scal[S_PAP + i] = 0.f;
}

__global__ void k_pupd_nm(const float* __restrict__ r, float* __restrict__ p,
                          const float* __restrict__ scal, int n4tot){
  if (*(const int*)(scal + S_FLAG)) return;
  int i = blockIdx.x * blockDim.x + threadIdx.x;
  if (i >= n4tot) return;
  int b = (i >> 1) & 7;
  float be = scal[S_BETA + b];
  f4 rv = ((const f4*)r)[i];
  f4 pv = ((f4*)p)[i];
  pv = rv + be * pv;
  ((f4*)p)[i] = pv;
}

// ---------------- minimal fallback tier (batch-major, R-direct) ----------------
#define OS_RSOLD 0
#define OS_PAP   8
#define OS_RSNEW 16
#define OS_ALPHA 24
#define OS_BETA  32
#define OS_FLAG  40

__device__ __forceinline__ float blk_reduce_256(float v){
  __shared__ float sm[4];
  #pragma unroll
  for (int o = 32; o > 0; o >>= 1) v += __shfl_down(v, o, 64);
  int lane = threadIdx.x & 63, w = threadIdx.x >> 6;
  if (lane == 0) sm[w] = v;
  __syncthreads();
  return (threadIdx.x == 0) ? (sm[0] + sm[1] + sm[2] + sm[3]) : 0.f;
}

__global__ void k_setup_fb(float* scal){
  int i = blockIdx.x * blockDim.x + threadIdx.x;
  if (i < 64) scal[i] = 0.f;
}

__global__ void k_apinit(const float* __restrict__ in, float* __restrict__ out,
                         int n4tot, const int* __restrict__ flag){
  if (*flag) return;
  int j = blockIdx.x * blockDim.x + threadIdx.x;
  if (j < n4tot) ((f4*)out)[j] = ((const f4*)in)[j];
}

__global__ void k_mv_edge_fb(const float* __restrict__ Rs, const float* __restrict__ Rd,
                             const int* __restrict__ src, const int* __restrict__ dst,
                             const float* __restrict__ in, float* __restrict__ out,
                             int Mn, int E, const int* __restrict__ flag){
  if (*flag) return;
  int g  = blockIdx.x * blockDim.x + threadIdx.x;
  int wv = g >> 6, l = g & 63;
  int nw = (gridDim.x * blockDim.x) >> 6;
  int b = l >> 3, q = l & 7;
  for (int e = wv; e < E; e += nw){
    int s = src[e], t = dst[e];
    const f4* rs4 = (const f4*)(Rs + (size_t)e * 64 + q * 8);
    const f4* rd4 = (const f4*)(Rd + (size_t)e * 64 + q * 8);
    const f4* ps4 = (const f4*)(in + ((size_t)b * Mn + s) * 8);
    const f4* pd4 = (const f4*)(in + ((size_t)b * Mn + t) * 8);
    f4 ra0 = rs4[0], ra1 = rs4[1], pa0 = ps4[0], pa1 = ps4[1];
    f4 rb0 = rd4[0], rb1 = rd4[1], pb0 = pd4[0], pb1 = pd4[1];
    float re = dot8v(ra0, ra1, pa0, pa1) - dot8v(rb0, rb1, pb0, pb1);
    float cs = 0.f, cd = 0.f;
    #pragma unroll
    for (int a = 0; a < 8; ++a){
      float rea = __shfl(re, b * 8 + a, 64);
      cs += Rs[(size_t)e * 64 + a * 8 + q] * rea;
      cd += Rd[(size_t)e * 64 + a * 8 + q] * rea;
    }
    atomicAdd(&out[((size_t)b * Mn + s) * 8 + q],  LAM * cs);
    atomicAdd(&out[((size_t)b * Mn + t) * 8 + q], -LAM * cd);
  }
}

__global__ void k_init_o(const float* __restrict__ c0, const float* __restrict__ Ap,
                         float* __restrict__ x, float* __restrict__ r, float* __restrict__ p,
                         float* scal, int n4){
  int b = blockIdx.y;
  size_t base = (size_t)b * n4;
  int j = blockIdx.x * blockDim.x + threadIdx.x;
  float part = 0.f;
  if (j < n4){
    f4 cv = ((const f4*)c0)[base + j];
    f4 av = ((const f4*)Ap)[base + j];
    f4 rv = cv - av;
    ((f4*)x)[base + j] = cv;
    ((f4*)r)[base + j] = rv;
    ((f4*)p)[base + j] = rv;
    part = rv[0]*rv[0] + rv[1]*rv[1] + rv[2]*rv[2] + rv[3]*rv[3];
  }
  float tot = blk_reduce_256(part);
  if (threadIdx.x == 0) atomicAdd(&scal[OS_RSOLD + b], tot);
}

__global__ void k_dot_o(const float* __restrict__ p, const float* __restrict__ Ap,
                        float* scal, int n4){
  const int* flag = (const int*)(scal + OS_FLAG);
  if (*flag) return;
  int b = blockIdx.y;
  size_t base = (size_t)b * n4;
  int j = blockIdx.x * blockDim.x + threadIdx.x;
  float part = 0.f;
  if (j < n4){
    f4 pv = ((const f4*)p)[base + j];
    f4 av = ((const f4*)Ap)[base + j];
    part = pv[0]*av[0] + pv[1]*av[1] + pv[2]*av[2] + pv[3]*av[3];
  }
  float tot = blk_reduce_256(part);
  if (threadIdx.x == 0) atomicAdd(&scal[OS_PAP + b], tot);
}

__global__ void k_s1_o(float* scal){
  const int* flag = (const int*)(scal + OS_FLAG);
  if (*flag) return;
  int t = threadIdx.x;
  if (t < 8){
    scal[OS_ALPHA + t] = scal[OS_RSOLD + t] / (scal[OS_PAP + t] + 1e-12f);
    scal[OS_RSNEW + t] = 0.f;
  }
}

__global__ void k_upd_o(float* __restrict__ x, float* __restrict__ r,
                        const float* __restrict__ p, const float* __restrict__ Ap,
                        float* scal, int n4){
  const int* flag = (const int*)(scal + OS_FLAG);
  if (*flag) return;
  int b = blockIdx.y;
  size_t base = (size_t)b * n4;
  float al = scal[OS_ALPHA + b];
  int j = blockIdx.x * blockDim.x + threadIdx.x;
  float part = 0.f;
  if (j < n4){
    f4 pv = ((const f4*)p)[base + j];
    f4 av = ((const f4*)Ap)[base + j];
    f4 xv = ((f4*)x)[base + j];
    f4 rv = ((f4*)r)[base + j];
    xv += al * pv;
    rv -= al * av;
    ((f4*)x)[base + j] = xv;
    ((f4*)r)[base + j] = rv;
    part = rv[0]*rv[0] + rv[1]*rv[1] + rv[2]*rv[2] + rv[3]*rv[3];
  }
  float tot = blk_reduce_256(part);
  if (threadIdx.x == 0) atomicAdd(&scal[OS_RSNEW + b], tot);
}

__global__ void k_s2_o(float* scal){
  int* flag = (int*)(scal + OS_FLAG);
  if (*flag) return;
  if (threadIdx.x == 0){
    float ssum = 0.f;
    for (int bb = 0; bb < 8; ++bb) ssum += scal[OS_RSNEW + bb];
    if (sqrtf(ssum / 8.0f) < TOL){
      *flag = 1;
    } else {
      for (int bb = 0; bb < 8; ++bb){
        scal[OS_BETA + bb]  = scal[OS_RSNEW + bb] / (scal[OS_RSOLD + bb] + 1e-12f);
        scal[OS_RSOLD + bb] = scal[OS_RSNEW + bb];
        scal[OS_PAP + bb]   = 0.f;
      }
    }
  }
}

__global__ void k_pupd_o(const float* __restrict__ r, float* __restrict__ p,
                         float* scal, int n4){
  const int* flag = (const int*)(scal + OS_FLAG);
  if (*flag) return;
  int b = blockIdx.y;
  size_t base = (size_t)b * n4;
  float be = scal[OS_BETA + b];
  int j = blockIdx.x * blockDim.x + threadIdx.x;
  if (j < n4){
    f4 rv = ((const f4*)r)[base + j];
    f4 pv = ((f4*)p)[base + j];
    pv = rv + be * pv;
    ((f4*)p)[base + j] = pv;
  }
}

// ---------------- launch ----------------
extern "C" void kernel_launch(void* const* d_in, const int* in_sizes, int n_in,
                              void* d_out, int out_size, void* d_ws, size_t ws_size,
                              hipStream_t stream){
  const float* c0  = (const float*)d_in[0];
  const int*   src = (const int*)d_in[1];
  const int*   dst = (const int*)d_in[2];
  const float* Rs  = (const float*)d_in[3];
  const float* Rd  = (const float*)d_in[4];

  int N  = in_sizes[0];          // B*Mn*8 floats, B=8, d=8
  int Mn = N / 64;
  int E  = in_sizes[1];
  int n4tot = N / 4;
  int twoEM = 2 * E + Mn;        // neighbor slots + diagonal slots

  float* ws = (float*)d_ws;
  size_t off = 0;
  float* r    = ws + off;  off += N;
  float* p    = ws + off;  off += N;
  float* Ap   = ws + off;  off += N;
  float* scal = ws + off;  off += SCAL_F;
  int* rowptr = (int*)(ws + off);  off += (size_t)((Mn + 1 + 3) & ~3);
  int* cursor = (int*)(ws + off);  off += (size_t)((Mn + 3) & ~3);
  int* colA   = (int*)(ws + off);  off += (size_t)(twoEM + 8);
  int* esA    = (int*)(ws + off);  off += (size_t)twoEM;
  float* Bcsr = ws + off;  off += (size_t)(twoEM + 8) * 64;   // +8 pad slots
  size_t need_main = off * 4;

  int nb_vec  = (n4tot + 255) / 256;
  int nb_node = (Mn * 64 + 255) / 256;

  if (ws_size >= need_main){
    k_setup_nm<<<512, 256, 0, stream>>>(scal, cursor, Mn);
    k_deg  <<<1024, 256, 0, stream>>>(src, dst, cursor, E);
    k_scan <<<1, 1024, 0, stream>>>(cursor, rowptr, cursor, Mn, twoEM);
    // tile-sorted fill: one pass per col-tile so each row's slots are grouped
    // by ascending col-tile (cache-blocked gathers in k_mv)
    for (int t0 = 0; t0 < Mn; t0 += TILE){
      int t1 = t0 + TILE; if (t1 > Mn) t1 = Mn;
      k_fill_t<<<1024, 256, 0, stream>>>(src, dst, cursor, colA, esA, E, t0, t1);
    }
    k_buildg<<<nb_node, 256, 0, stream>>>(Rs, Rd, rowptr, esA, Bcsr, colA, Mn);

    float* x_bm = (float*)d_out;
    k_perm<<<nb_vec, 256, 0, stream>>>(c0, p, Mn);   // p := c0 (node-major)
    k_mv<<<nb_node, 256, 0, stream>>>(Bcsr, rowptr, colA, p, Ap, scal, Mn);
    k_init_nm<<<nb_vec, 256, 0, stream>>>(p, Ap, r, x_bm, scal, n4tot, Mn);
    k_s0<<<1, 256, 0, stream>>>(scal);

    for (int it = 0; it < NIT; ++it){
      k_mv<<<nb_node, 256, 0, stream>>>(Bcsr, rowptr, colA, p, Ap, scal, Mn);
      k_alpha<<<1, 256, 0, stream>>>(scal);
      k_upd_nm<<<nb_vec, 256, 0, stream>>>(x_bm, r, p, Ap, scal, n4tot, Mn);
      k_s2<<<1, 256, 0, stream>>>(scal);
      k_pupd_nm<<<nb_vec, 256, 0, stream>>>(r, p, scal, n4tot);
    }
  } else {
    // fallback: batch-major R-direct (needs 3N+64 floats)
    float* fr    = ws;
    float* fp    = fr + N;
    float* fAp   = fp + N;
    float* fscal = fAp + N;
    const int* flagp = (const int*)(fscal + OS_FLAG);
    int n4 = Mn * 2;
    dim3 vgrid((n4 + 255) / 256, 8);
    int cb = (n4tot + 255) / 256;
    float* x = (float*)d_out;

    k_setup_fb<<<1, 64, 0, stream>>>(fscal);
    k_apinit<<<cb, 256, 0, stream>>>(c0, fAp, n4tot, flagp);
    k_mv_edge_fb<<<2048, 256, 0, stream>>>(Rs, Rd, src, dst, c0, fAp, Mn, E, flagp);
    k_init_o<<<vgrid, 256, 0, stream>>>(c0, fAp, x, fr, fp, fscal, n4);
    for (int it = 0; it < NIT; ++it){
      k_apinit<<<cb, 256, 0, stream>>>(fp, fAp, n4tot, flagp);
      k_mv_edge_fb<<<2048, 256, 0, stream>>>(Rs, Rd, src, dst, fp, fAp, Mn, E, flagp);
      k_dot_o<<<vgrid, 256, 0, stream>>>(fp, fAp, fscal, n4);
      k_s1_o<<<1, 64, 0, stream>>>(fscal);
      k_upd_o<<<vgrid, 256, 0, stream>>>(x, fr, fp, fAp, fscal, n4);
      k_s2_o<<<1, 64, 0, stream>>>(fscal);
      k_pupd_o<<<vgrid, 256, 0, stream>>>(fr, fp, fscal, n4);
    }
  }
}

// Round 7
// 5144.995 us; speedup vs baseline: 1.1242x; 1.1242x over previous
//
#include <hip/hip_runtime.h>
#include <math.h>

constexpr float LAM = 1.0f;
constexpr int   NIT = 20;
constexpr float TOL = 1e-6f;

typedef float f4 __attribute__((ext_vector_type(4)));

// ---------------- scal layout (floats) ----------------
#define S_RSOLD 0
#define S_ALPHA 8
#define S_BETA  16
#define S_FLAG  24        // int alias
#define S_PAP   32        // [8][256] partial slots for p.Ap
#define S_RS    (32+2048) // [8][256] partial slots for r.r
#define SCAL_F  (32+4096)

__device__ __forceinline__ float dot8v(f4 a0, f4 a1, f4 b0, f4 b1){
  return a0[0]*b0[0] + a0[1]*b0[1] + a0[2]*b0[2] + a0[3]*b0[3]
       + a1[0]*b1[0] + a1[1]*b1[1] + a1[2]*b1[2] + a1[3]*b1[3];
}

// zero scal, zero cursor
__global__ void k_setup_nm(float* __restrict__ scal, int* __restrict__ cursor, int Mn){
  int i = blockIdx.x * blockDim.x + threadIdx.x;
  int stride = gridDim.x * blockDim.x;
  for (int j = i; j < SCAL_F; j += stride) scal[j] = 0.f;
  for (int j = i; j < Mn; j += stride) cursor[j] = 0;
}

__global__ void k_deg(const int* __restrict__ src, const int* __restrict__ dst,
                      int* __restrict__ cnt, int E){
  int i = blockIdx.x * blockDim.x + threadIdx.x;
  int stride = gridDim.x * blockDim.x;
  for (int e = i; e < E; e += stride){
    atomicAdd(&cnt[src[e]], 1);
    atomicAdd(&cnt[dst[e]], 1);
  }
}

// exclusive scan of degrees -> rowptr; cursor = rowptr
__global__ void k_scan(int* __restrict__ cnt, int* __restrict__ rowptr,
                       int* __restrict__ cursor, int Mn, int tot){
  __shared__ int sm[1024];
  const int T = 1024;
  int t = threadIdx.x;
  int chunk = (Mn + T - 1) / T;
  int lo = t * chunk, hi = lo + chunk; if (hi > Mn) hi = Mn;
  int s = 0;
  for (int i = lo; i < hi; ++i) s += cnt[i];
  sm[t] = s;
  __syncthreads();
  for (int o = 1; o < T; o <<= 1){
    int v = (t >= o) ? sm[t - o] : 0;
    __syncthreads();
    sm[t] += v;
    __syncthreads();
  }
  int base = (t == 0) ? 0 : sm[t - 1];
  for (int i = lo; i < hi; ++i){
    int c = cnt[i];
    rowptr[i] = base;
    cursor[i] = base;
    base += c;
  }
  if (t == T - 1) rowptr[Mn] = tot;
}

// fill CSR neighbor slots: col[slot]=partner, es[slot]=(e<<1)|side
__global__ void k_fill(const int* __restrict__ src, const int* __restrict__ dst,
                       int* __restrict__ cursor, int* __restrict__ col,
                       int* __restrict__ es, int E){
  int i = blockIdx.x * blockDim.x + threadIdx.x;
  int stride = gridDim.x * blockDim.x;
  for (int e = i; e < E; e += stride){
    int s = src[e], t = dst[e];
    int ps = atomicAdd(&cursor[s], 1);
    col[ps] = t; es[ps] = (e << 1);
    int pt = atomicAdd(&cursor[t], 1);
    col[pt] = s; es[pt] = (e << 1) | 1;
  }
}

// edge-order sequential M build: M[e] = Rs[e]^T Rd[e]. Pure stream, no atomics.
// Plain (cached) stores so M lands in L2/L3 for the matvecs.
__global__ void k_medge(const float* __restrict__ Rs, const float* __restrict__ Rd,
                        float* __restrict__ Mb, int E){
  int g  = blockIdx.x * blockDim.x + threadIdx.x;
  int wv = g >> 6, l = g & 63;
  int nw = (gridDim.x * blockDim.x) >> 6;
  int d1 = l >> 3, d2 = l & 7;
  for (int e = wv; e < E; e += nw){
    float rs = Rs[(size_t)e * 64 + l];
    float rd = Rd[(size_t)e * 64 + l];
    float Mm = 0.f;
    #pragma unroll
    for (int a = 0; a < 8; ++a)
      Mm += __shfl(rs, a * 8 + d1, 64) * __shfl(rd, a * 8 + d2, 64);
    Mb[(size_t)e * 64 + l] = Mm;
  }
}

// D build (gather side): wave per node in [v0,v1), lane l=(d1,d2).
// Loads only the side-matching R row per slot (halves bytes vs old buildg).
__global__ void k_buildd(const float* __restrict__ Rs, const float* __restrict__ Rd,
                         const int* __restrict__ rowptr, const int* __restrict__ es,
                         float* __restrict__ Dd, int v0, int v1){
  int g = blockIdx.x * blockDim.x + threadIdx.x;
  int v = v0 + (g >> 6);
  if (v >= v1) return;
  int l = g & 63, d1 = l >> 3, d2 = l & 7;
  float Dacc = 0.f;
  int j0 = rowptr[v], j1 = rowptr[v + 1];
  int j = j0;
  for (; j + 2 <= j1; j += 2){
    int e0 = es[j], e1 = es[j + 1];
    const float* R0 = (e0 & 1) ? Rd : Rs;
    const float* R1 = (e1 & 1) ? Rd : Rs;
    float x0 = R0[(size_t)(e0 >> 1) * 64 + l];
    float x1 = R1[(size_t)(e1 >> 1) * 64 + l];
    #pragma unroll
    for (int a = 0; a < 8; ++a){
      float p0 = __shfl(x0, a * 8 + d1, 64);
      float s0 = __shfl(x0, a * 8 + d2, 64);
      float p1 = __shfl(x1, a * 8 + d1, 64);
      float s1 = __shfl(x1, a * 8 + d2, 64);
      Dacc += p0 * s0 + p1 * s1;
    }
  }
  for (; j < j1; ++j){
    int e0 = es[j];
    const float* R0 = (e0 & 1) ? Rd : Rs;
    float x0 = R0[(size_t)(e0 >> 1) * 64 + l];
    #pragma unroll
    for (int a = 0; a < 8; ++a)
      Dacc += __shfl(x0, a * 8 + d1, 64) * __shfl(x0, a * 8 + d2, 64);
  }
  Dd[(size_t)v * 64 + l] = ((d1 == d2) ? 1.f : 0.f) + LAM * Dacc;
}

// wave per node. Two-phase, LDS-staged, double-buffered M-form matvec.
// Phase A (lane=(hi,lo)): gather segment lo of p[col[..]] AND M[e[..]] -> LDS.
// Phase B (lane=(b=hi,dd=lo)): acc -= LAM * (M|M^T) p, side branch wave-uniform.
// M reads are plain (cached): 204.8 MB fits the 256 MB L3 across all matvecs.
__global__ void k_mv(const float* __restrict__ Mb, const float* __restrict__ Dd,
                     const int* __restrict__ rowptr, const int* __restrict__ col,
                     const int* __restrict__ es, const float* __restrict__ p,
                     float* __restrict__ out, float* __restrict__ scal, int Mn){
  if (*(const int*)(scal + S_FLAG)) return;
  __shared__ float pbuf[4][2][8][64];
  __shared__ float mbuf[4][2][8][64];
  __shared__ int   cbuf[4][128];
  __shared__ int   ebuf[4][128];
  int g = blockIdx.x * blockDim.x + threadIdx.x;
  int v = g >> 6;
  bool active = (v < Mn);
  int w  = threadIdx.x >> 6;
  int l  = g & 63;
  int hi = l >> 3, lo = l & 7;
  int k8 = lo * 8;          // phase-A segment offset / phase-B row offset (dd*8)
  int b8 = hi * 8;          // phase-B batch offset
  int j0 = 0, j1 = 0, rowlen = 0;
  if (active){
    j0 = rowptr[v]; j1 = rowptr[v + 1];
    rowlen = j1 - j0;
    for (int jj = l; jj < rowlen && jj < 128; jj += 64){
      cbuf[w][jj] = col[j0 + jj];
      ebuf[w][jj] = es[j0 + jj];
    }
  }
  __syncthreads();
  if (!active) return;

  int nch = (rowlen + 7) >> 3;

  auto gather = [&](int n, f4& gp0, f4& gp1, f4& gm0, f4& gm1){
    int jj = n * 8 + hi;
    int c = v, e = 0;
    if (jj < rowlen){
      if (jj < 128){ c = cbuf[w][jj]; e = ebuf[w][jj] >> 1; }
      else         { c = col[j0 + jj]; e = es[j0 + jj] >> 1; }
    }
    const float* pc = p + (size_t)c * 64 + k8;
    gp0 = *(const f4*)pc;
    gp1 = *(const f4*)(pc + 4);
    const float* mc = Mb + (size_t)e * 64 + k8;
    gm0 = *(const f4*)mc;
    gm1 = *(const f4*)(mc + 4);
  };

  // acc = D_v p_v   (D row dd=lo; p row b=hi)
  const f4* pv4 = (const f4*)(p + (size_t)v * 64 + b8);
  f4 pv0 = pv4[0], pv1 = pv4[1];
  const f4* dr4 = (const f4*)(Dd + (size_t)v * 64 + k8);
  float acc = dot8v(dr4[0], dr4[1], pv0, pv1);

  if (nch > 0){
    f4 u0, u1, m0, m1;
    gather(0, u0, u1, m0, m1);
    float* dp = &pbuf[w][0][hi][k8];
    *(f4*)dp = u0; *(f4*)(dp + 4) = u1;
    float* dm = &mbuf[w][0][hi][k8];
    *(f4*)dm = m0; *(f4*)(dm + 4) = m1;
  }

  for (int n = 0; n < nch; ++n){
    int nb = n & 1;
    bool more = (n + 1 < nch);
    f4 gp0, gp1, gm0, gm1;
    if (more) gather(n + 1, gp0, gp1, gm0, gm1);
    int jb = n * 8;
    int lim = rowlen - jb;           // slots in this chunk (may exceed 8 only capped)
    #pragma unroll
    for (int q = 0; q < 8; ++q){
      if (q < lim){
        int jj = jb + q;
        int sd = ((jj < 128) ? ebuf[w][jj] : es[j0 + jj]) & 1;   // wave-uniform
        const float* pr = &pbuf[w][nb][q][b8];
        f4 q0 = *(const f4*)pr, q1 = *(const f4*)(pr + 4);
        const float* mc = &mbuf[w][nb][q][0];
        if (!sd){
          f4 m0 = *(const f4*)(mc + k8);
          f4 m1 = *(const f4*)(mc + k8 + 4);
          acc -= LAM * dot8v(m0, m1, q0, q1);
        } else {
          acc -= LAM * ( mc[lo]      * q0[0] + mc[lo +  8] * q0[1]
                       + mc[lo + 16] * q0[2] + mc[lo + 24] * q0[3]
                       + mc[lo + 32] * q1[0] + mc[lo + 40] * q1[1]
                       + mc[lo + 48] * q1[2] + mc[lo + 56] * q1[3]);
        }
      }
    }
    if (more){
      float* dp = &pbuf[w][nb ^ 1][hi][k8];
      *(f4*)dp = gp0; *(f4*)(dp + 4) = gp1;
      float* dm = &mbuf[w][nb ^ 1][hi][k8];
      *(f4*)dm = gm0; *(f4*)(dm + 4) = gm1;
    }
  }
  out[(size_t)v * 64 + l] = acc;
  // fused p.Ap partial: p element at (v, hi*8+lo) from pv regs
  float pself = (lo & 4) ? ((lo & 2) ? ((lo & 1) ? pv1[3] : pv1[2])
                                     : ((lo & 1) ? pv1[1] : pv1[0]))
                         : ((lo & 2) ? ((lo & 1) ? pv0[3] : pv0[2])
                                     : ((lo & 1) ? pv0[1] : pv0[0]));
  float part = pself * acc;
  part += __shfl_xor(part, 1, 64);
  part += __shfl_xor(part, 2, 64);
  part += __shfl_xor(part, 4, 64);
  if (lo == 0)
    atomicAdd(&scal[S_PAP + hi * 256 + (blockIdx.x & 255)], part);
}

// c0 (batch-major) -> node-major buffer
__global__ void k_perm(const float* __restrict__ c0, float* __restrict__ xp, int Mn){
  int i = blockIdx.x * blockDim.x + threadIdx.x;
  int n4 = Mn * 16;
  if (i >= n4) return;
  int v = i >> 4, rem = i & 15, b = rem >> 1, half = rem & 1;
  f4 cv = *(const f4*)(c0 + ((size_t)b * Mn + v) * 8 + half * 4);
  ((f4*)xp)[i] = cv;
}

// r = c0p - Ap; p = r (in place over c0p); x (batch-major, d_out) = c0
__global__ void k_init_nm(float* __restrict__ p, const float* __restrict__ Ap,
                          float* __restrict__ r, float* __restrict__ x_bm,
                          float* __restrict__ scal, int n4tot, int Mn){
  int i = blockIdx.x * blockDim.x + threadIdx.x;
  int l = threadIdx.x & 63;
  float part = 0.f;
  if (i < n4tot){
    f4 cv = ((const f4*)p)[i];
    f4 av = ((const f4*)Ap)[i];
    f4 rv = cv - av;
    ((f4*)r)[i] = rv;
    ((f4*)p)[i] = rv;
    int v = i >> 4, rem = i & 15, b = rem >> 1, half = rem & 1;
    ((f4*)x_bm)[((size_t)b * Mn + v) * 2 + half] = cv;
    part = rv[0]*rv[0] + rv[1]*rv[1] + rv[2]*rv[2] + rv[3]*rv[3];
  }
  part += __shfl_xor(part, 1, 64);
  part += __shfl_xor(part, 16, 64);
  part += __shfl_xor(part, 32, 64);
  if ((l & 49) == 0)
    atomicAdd(&scal[S_RS + ((l >> 1) & 7) * 256 + (blockIdx.x & 255)], part);
}

// once: RSOLD[b] = sum(S_RS); zero both slot arrays
__global__ void k_s0(float* __restrict__ scal){
  __shared__ float sm[256];
  int t = threadIdx.x;
  int b = t >> 5, k0 = t & 31;
  float s = 0.f;
  #pragma unroll
  for (int i = 0; i < 8; ++i) s += scal[S_RS + b * 256 + k0 + i * 32];
  sm[t] = s;
  __syncthreads();
  if (t < 8){
    float tot = 0.f;
    #pragma unroll
    for (int i = 0; i < 32; ++i) tot += sm[t * 32 + i];
    scal[S_RSOLD + t] = tot;
  }
  __syncthreads();
  for (int i = t; i < 4096; i += 256) scal[S_PAP + i] = 0.f;
}

// alpha[b] = rsold[b] / (sum S_PAP slots + eps)
__global__ void k_alpha(float* __restrict__ scal){
  if (*(const int*)(scal + S_FLAG)) return;
  __shared__ float sm[256];
  int t = threadIdx.x;
  int b = t >> 5, k0 = t & 31;
  float s = 0.f;
  #pragma unroll
  for (int i = 0; i < 8; ++i) s += scal[S_PAP + b * 256 + k0 + i * 32];
  sm[t] = s;
  __syncthreads();
  if (t < 8){
    float tot = 0.f;
    #pragma unroll
    for (int i = 0; i < 32; ++i) tot += sm[t * 32 + i];
    scal[S_ALPHA + t] = scal[S_RSOLD + t] / (tot + 1e-12f);
  }
}

// x(batch-major) += a p; r -= a Ap; accumulate rnew.rnew
__global__ void k_upd_nm(float* __restrict__ x_bm, float* __restrict__ r,
                         const float* __restrict__ p, const float* __restrict__ Ap,
                         float* __restrict__ scal, int n4tot, int Mn){
  if (*(const int*)(scal + S_FLAG)) return;
  int i = blockIdx.x * blockDim.x + threadIdx.x;
  int l = threadIdx.x & 63;
  float part = 0.f;
  if (i < n4tot){
    int v = i >> 4, rem = i & 15, b = rem >> 1, half = rem & 1;
    float al = scal[S_ALPHA + b];
    size_t xi = ((size_t)b * Mn + v) * 2 + half;
    f4 pv = ((const f4*)p)[i];
    f4 av = ((const f4*)Ap)[i];
    f4 xv = ((f4*)x_bm)[xi];
    f4 rv = ((f4*)r)[i];
    xv += al * pv;
    rv -= al * av;
    ((f4*)x_bm)[xi] = xv;
    ((f4*)r)[i] = rv;
    part = rv[0]*rv[0] + rv[1]*rv[1] + rv[2]*rv[2] + rv[3]*rv[3];
  }
  part += __shfl_xor(part, 1, 64);
  part += __shfl_xor(part, 16, 64);
  part += __shfl_xor(part, 32, 64);
  if ((l & 49) == 0)
    atomicAdd(&scal[S_RS + ((l >> 1) & 7) * 256 + (blockIdx.x & 255)], part);
}

// rsnew from S_RS; conv flag; BETA/RSOLD; zero slot arrays
__global__ void k_s2(float* __restrict__ scal){
  if (*(const int*)(scal + S_FLAG)) return;
  __shared__ float sm[256];
  __shared__ float rsn[8];
  int t = threadIdx.x;
  int b = t >> 5, k0 = t & 31;
  float s = 0.f;
  #pragma unroll
  for (int i = 0; i < 8; ++i) s += scal[S_RS + b * 256 + k0 + i * 32];
  sm[t] = s;
  __syncthreads();
  if (t < 8){
    float tot = 0.f;
    #pragma unroll
    for (int i = 0; i < 32; ++i) tot += sm[t * 32 + i];
    rsn[t] = tot;
  }
  __syncthreads();
  if (t == 0){
    float ssum = 0.f;
    for (int bb = 0; bb < 8; ++bb) ssum += rsn[bb];
    if (sqrtf(ssum / 8.0f) < TOL){
      *(int*)(scal + S_FLAG) = 1;   // freeze
    } else {
      for (int bb = 0; bb < 8; ++bb){
        scal[S_BETA + bb]  = rsn[bb] / (scal[S_RSOLD + bb] + 1e-12f);
        scal[S_RSOLD + bb] = rsn[bb];
      }
    }
  }
  __syncthreads();
  for (int i = t; i < 4096; i += 256) scal[S_PAP + i] = 0.f;
}

__global__ void k_pupd_nm(const float* __restrict__ r, float* __restrict__ p,
                          const float* __restrict__ scal, int n4tot){
  if (*(const int*)(scal + S_FLAG)) return;
  int i = blockIdx.x * blockDim.x + threadIdx.x;
  if (i >= n4tot) return;
  int b = (i >> 1) & 7;
  float be = scal[S_BETA + b];
  f4 rv = ((const f4*)r)[i];
  f4 pv = ((f4*)p)[i];
  pv = rv + be * pv;
  ((f4*)p)[i] = pv;
}

// ---------------- minimal fallback tier (batch-major, R-direct) ----------------
#define OS_RSOLD 0
#define OS_PAP   8
#define OS_RSNEW 16
#define OS_ALPHA 24
#define OS_BETA  32
#define OS_FLAG  40

__device__ __forceinline__ float blk_reduce_256(float v){
  __shared__ float sm[4];
  #pragma unroll
  for (int o = 32; o > 0; o >>= 1) v += __shfl_down(v, o, 64);
  int lane = threadIdx.x & 63, w = threadIdx.x >> 6;
  if (lane == 0) sm[w] = v;
  __syncthreads();
  return (threadIdx.x == 0) ? (sm[0] + sm[1] + sm[2] + sm[3]) : 0.f;
}

__global__ void k_setup_fb(float* scal){
  int i = blockIdx.x * blockDim.x + threadIdx.x;
  if (i < 64) scal[i] = 0.f;
}

__global__ void k_apinit(const float* __restrict__ in, float* __restrict__ out,
                         int n4tot, const int* __restrict__ flag){
  if (*flag) return;
  int j = blockIdx.x * blockDim.x + threadIdx.x;
  if (j < n4tot) ((f4*)out)[j] = ((const f4*)in)[j];
}

__global__ void k_mv_edge_fb(const float* __restrict__ Rs, const float* __restrict__ Rd,
                             const int* __restrict__ src, const int* __restrict__ dst,
                             const float* __restrict__ in, float* __restrict__ out,
                             int Mn, int E, const int* __restrict__ flag){
  if (*flag) return;
  int g  = blockIdx.x * blockDim.x + threadIdx.x;
  int wv = g >> 6, l = g & 63;
  int nw = (gridDim.x * blockDim.x) >> 6;
  int b = l >> 3, q = l & 7;
  for (int e = wv; e < E; e += nw){
    int s = src[e], t = dst[e];
    const f4* rs4 = (const f4*)(Rs + (size_t)e * 64 + q * 8);
    const f4* rd4 = (const f4*)(Rd + (size_t)e * 64 + q * 8);
    const f4* ps4 = (const f4*)(in + ((size_t)b * Mn + s) * 8);
    const f4* pd4 = (const f4*)(in + ((size_t)b * Mn + t) * 8);
    f4 ra0 = rs4[0], ra1 = rs4[1], pa0 = ps4[0], pa1 = ps4[1];
    f4 rb0 = rd4[0], rb1 = rd4[1], pb0 = pd4[0], pb1 = pd4[1];
    float re = dot8v(ra0, ra1, pa0, pa1) - dot8v(rb0, rb1, pb0, pb1);
    float cs = 0.f, cd = 0.f;
    #pragma unroll
    for (int a = 0; a < 8; ++a){
      float rea = __shfl(re, b * 8 + a, 64);
      cs += Rs[(size_t)e * 64 + a * 8 + q] * rea;
      cd += Rd[(size_t)e * 64 + a * 8 + q] * rea;
    }
    atomicAdd(&out[((size_t)b * Mn + s) * 8 + q],  LAM * cs);
    atomicAdd(&out[((size_t)b * Mn + t) * 8 + q], -LAM * cd);
  }
}

__global__ void k_init_o(const float* __restrict__ c0, const float* __restrict__ Ap,
                         float* __restrict__ x, float* __restrict__ r, float* __restrict__ p,
                         float* scal, int n4){
  int b = blockIdx.y;
  size_t base = (size_t)b * n4;
  int j = blockIdx.x * blockDim.x + threadIdx.x;
  float part = 0.f;
  if (j < n4){
    f4 cv = ((const f4*)c0)[base + j];
    f4 av = ((const f4*)Ap)[base + j];
    f4 rv = cv - av;
    ((f4*)x)[base + j] = cv;
    ((f4*)r)[base + j] = rv;
    ((f4*)p)[base + j] = rv;
    part = rv[0]*rv[0] + rv[1]*rv[1] + rv[2]*rv[2] + rv[3]*rv[3];
  }
  float tot = blk_reduce_256(part);
  if (threadIdx.x == 0) atomicAdd(&scal[OS_RSOLD + b], tot);
}

__global__ void k_dot_o(const float* __restrict__ p, const float* __restrict__ Ap,
                        float* scal, int n4){
  const int* flag = (const int*)(scal + OS_FLAG);
  if (*flag) return;
  int b = blockIdx.y;
  size_t base = (size_t)b * n4;
  int j = blockIdx.x * blockDim.x + threadIdx.x;
  float part = 0.f;
  if (j < n4){
    f4 pv = ((const f4*)p)[base + j];
    f4 av = ((const f4*)Ap)[base + j];
    part = pv[0]*av[0] + pv[1]*av[1] + pv[2]*av[2] + pv[3]*av[3];
  }
  float tot = blk_reduce_256(part);
  if (threadIdx.x == 0) atomicAdd(&scal[OS_PAP + b], tot);
}

__global__ void k_s1_o(float* scal){
  const int* flag = (const int*)(scal + OS_FLAG);
  if (*flag) return;
  int t = threadIdx.x;
  if (t < 8){
    scal[OS_ALPHA + t] = scal[OS_RSOLD + t] / (scal[OS_PAP + t] + 1e-12f);
    scal[OS_RSNEW + t] = 0.f;
  }
}

__global__ void k_upd_o(float* __restrict__ x, float* __restrict__ r,
                        const float* __restrict__ p, const float* __restrict__ Ap,
                        float* scal, int n4){
  const int* flag = (const int*)(scal + OS_FLAG);
  if (*flag) return;
  int b = blockIdx.y;
  size_t base = (size_t)b * n4;
  float al = scal[OS_ALPHA + b];
  int j = blockIdx.x * blockDim.x + threadIdx.x;
  float part = 0.f;
  if (j < n4){
    f4 pv = ((const f4*)p)[base + j];
    f4 av = ((const f4*)Ap)[base + j];
    f4 xv = ((f4*)x)[base + j];
    f4 rv = ((f4*)r)[base + j];
    xv += al * pv;
    rv -= al * av;
    ((f4*)x)[base + j] = xv;
    ((f4*)r)[base + j] = rv;
    part = rv[0]*rv[0] + rv[1]*rv[1] + rv[2]*rv[2] + rv[3]*rv[3];
  }
  float tot = blk_reduce_256(part);
  if (threadIdx.x == 0) atomicAdd(&scal[OS_RSNEW + b], tot);
}

__global__ void k_s2_o(float* scal){
  int* flag = (int*)(scal + OS_FLAG);
  if (*flag) return;
  if (threadIdx.x == 0){
    float ssum = 0.f;
    for (int bb = 0; bb < 8; ++bb) ssum += scal[OS_RSNEW + bb];
    if (sqrtf(ssum / 8.0f) < TOL){
      *flag = 1;
    } else {
      for (int bb = 0; bb < 8; ++bb){
        scal[OS_BETA + bb]  = scal[OS_RSNEW + bb] / (scal[OS_RSOLD + bb] + 1e-12f);
        scal[OS_RSOLD + bb] = scal[OS_RSNEW + bb];
        scal[OS_PAP + bb]   = 0.f;
      }
    }
  }
}

__global__ void k_pupd_o(const float* __restrict__ r, float* __restrict__ p,
                         float* scal, int n4){
  const int* flag = (const int*)(scal + OS_FLAG);
  if (*flag) return;
  int b = blockIdx.y;
  size_t base = (size_t)b * n4;
  float be = scal[OS_BETA + b];
  int j = blockIdx.x * blockDim.x + threadIdx.x;
  if (j < n4){
    f4 rv = ((const f4*)r)[base + j];
    f4 pv = ((f4*)p)[base + j];
    pv = rv + be * pv;
    ((f4*)p)[base + j] = pv;
  }
}

// ---------------- launch ----------------
extern "C" void kernel_launch(void* const* d_in, const int* in_sizes, int n_in,
                              void* d_out, int out_size, void* d_ws, size_t ws_size,
                              hipStream_t stream){
  const float* c0  = (const float*)d_in[0];
  const int*   src = (const int*)d_in[1];
  const int*   dst = (const int*)d_in[2];
  const float* Rs  = (const float*)d_in[3];
  const float* Rd  = (const float*)d_in[4];

  int N  = in_sizes[0];          // B*Mn*8 floats, B=8, d=8
  int Mn = N / 64;
  int E  = in_sizes[1];
  int n4tot = N / 4;
  int twoE = 2 * E;

  float* ws = (float*)d_ws;
  size_t off = 0;
  float* r    = ws + off;  off += N;
  float* p    = ws + off;  off += N;
  float* Ap   = ws + off;  off += N;
  float* scal = ws + off;  off += SCAL_F;
  float* Dd   = ws + off;  off += (size_t)Mn * 64;
  int* rowptr = (int*)(ws + off);  off += (size_t)((Mn + 1 + 3) & ~3);
  int* cursor = (int*)(ws + off);  off += (size_t)((Mn + 3) & ~3);
  int* colA   = (int*)(ws + off);  off += (size_t)twoE;
  int* esA    = (int*)(ws + off);  off += (size_t)twoE;
  float* Mb   = ws + off;  off += (size_t)E * 64;
  size_t need_main = off * 4;

  int nb_vec  = (n4tot + 255) / 256;
  int nb_node = (Mn * 64 + 255) / 256;

  if (ws_size >= need_main){
    k_setup_nm<<<512, 256, 0, stream>>>(scal, cursor, Mn);
    k_deg  <<<1024, 256, 0, stream>>>(src, dst, cursor, E);
    k_scan <<<1, 1024, 0, stream>>>(cursor, rowptr, cursor, Mn, twoE);
    k_fill <<<1024, 256, 0, stream>>>(src, dst, cursor, colA, esA, E);
    k_medge<<<4096, 256, 0, stream>>>(Rs, Rd, Mb, E);
    // D build split in two dispatches (profiling visibility + same total work)
    int Mh = (Mn + 1) / 2;
    int nb_h1 = (Mh * 64 + 255) / 256;
    int nb_h2 = ((Mn - Mh) * 64 + 255) / 256;
    k_buildd<<<nb_h1, 256, 0, stream>>>(Rs, Rd, rowptr, esA, Dd, 0, Mh);
    k_buildd<<<nb_h2, 256, 0, stream>>>(Rs, Rd, rowptr, esA, Dd, Mh, Mn);

    float* x_bm = (float*)d_out;
    k_perm<<<nb_vec, 256, 0, stream>>>(c0, p, Mn);   // p := c0 (node-major)
    k_mv<<<nb_node, 256, 0, stream>>>(Mb, Dd, rowptr, colA, esA, p, Ap, scal, Mn);
    k_init_nm<<<nb_vec, 256, 0, stream>>>(p, Ap, r, x_bm, scal, n4tot, Mn);
    k_s0<<<1, 256, 0, stream>>>(scal);

    for (int it = 0; it < NIT; ++it){
      k_mv<<<nb_node, 256, 0, stream>>>(Mb, Dd, rowptr, colA, esA, p, Ap, scal, Mn);
      k_alpha<<<1, 256, 0, stream>>>(scal);
      k_upd_nm<<<nb_vec, 256, 0, stream>>>(x_bm, r, p, Ap, scal, n4tot, Mn);
      k_s2<<<1, 256, 0, stream>>>(scal);
      k_pupd_nm<<<nb_vec, 256, 0, stream>>>(r, p, scal, n4tot);
    }
  } else {
    // fallback: batch-major R-direct (needs 3N+64 floats)
    float* fr    = ws;
    float* fp    = fr + N;
    float* fAp   = fp + N;
    float* fscal = fAp + N;
    const int* flagp = (const int*)(fscal + OS_FLAG);
    int n4 = Mn * 2;
    dim3 vgrid((n4 + 255) / 256, 8);
    int cb = (n4tot + 255) / 256;
    float* x = (float*)d_out;

    k_setup_fb<<<1, 64, 0, stream>>>(fscal);
    k_apinit<<<cb, 256, 0, stream>>>(c0, fAp, n4tot, flagp);
    k_mv_edge_fb<<<2048, 256, 0, stream>>>(Rs, Rd, src, dst, c0, fAp, Mn, E, flagp);
    k_init_o<<<vgrid, 256, 0, stream>>>(c0, fAp, x, fr, fp, fscal, n4);
    for (int it = 0; it < NIT; ++it){
      k_apinit<<<cb, 256, 0, stream>>>(fp, fAp, n4tot, flagp);
      k_mv_edge_fb<<<2048, 256, 0, stream>>>(Rs, Rd, src, dst, fp, fAp, Mn, E, flagp);
      k_dot_o<<<vgrid, 256, 0, stream>>>(fp, fAp, fscal, n4);
      k_s1_o<<<1, 64, 0, stream>>>(fscal);
      k_upd_o<<<vgrid, 256, 0, stream>>>(x, fr, fp, fAp, fscal, n4);
      k_s2_o<<<1, 64, 0, stream>>>(fscal);
      k_pupd_o<<<vgrid, 256, 0, stream>>>(fr, fp, fscal, n4);
    }
  }
}

// Round 8
// 5086.028 us; speedup vs baseline: 1.1372x; 1.0116x over previous
//
#include <hip/hip_runtime.h>
#include <math.h>

constexpr float LAM = 1.0f;
constexpr int   NIT = 20;
constexpr float TOL = 1e-6f;

typedef float f4 __attribute__((ext_vector_type(4)));

// ---------------- scal layout (floats) ----------------
#define S_RSOLD 0
#define S_ALPHA 8
#define S_BETA  16
#define S_FLAG  24        // int alias
#define S_PAP   32        // [8][256] partial slots for p.Ap
#define S_RS    (32+2048) // [8][256] partial slots for r.r
#define SCAL_F  (32+4096)

__device__ __forceinline__ float dot8v(f4 a0, f4 a1, f4 b0, f4 b1){
  return a0[0]*b0[0] + a0[1]*b0[1] + a0[2]*b0[2] + a0[3]*b0[3]
       + a1[0]*b1[0] + a1[1]*b1[1] + a1[2]*b1[2] + a1[3]*b1[3];
}

// zero scal, zero cursor
__global__ void k_setup_nm(float* __restrict__ scal, int* __restrict__ cursor, int Mn){
  int i = blockIdx.x * blockDim.x + threadIdx.x;
  int stride = gridDim.x * blockDim.x;
  for (int j = i; j < SCAL_F; j += stride) scal[j] = 0.f;
  for (int j = i; j < Mn; j += stride) cursor[j] = 0;
}

__global__ void k_deg(const int* __restrict__ src, const int* __restrict__ dst,
                      int* __restrict__ cnt, int E){
  int i = blockIdx.x * blockDim.x + threadIdx.x;
  int stride = gridDim.x * blockDim.x;
  for (int e = i; e < E; e += stride){
    atomicAdd(&cnt[src[e]], 1);
    atomicAdd(&cnt[dst[e]], 1);
  }
}

// exclusive scan of degrees -> rowptr; cursor = rowptr
__global__ void k_scan(int* __restrict__ cnt, int* __restrict__ rowptr,
                       int* __restrict__ cursor, int Mn, int tot){
  __shared__ int sm[1024];
  const int T = 1024;
  int t = threadIdx.x;
  int chunk = (Mn + T - 1) / T;
  int lo = t * chunk, hi = lo + chunk; if (hi > Mn) hi = Mn;
  int s = 0;
  for (int i = lo; i < hi; ++i) s += cnt[i];
  sm[t] = s;
  __syncthreads();
  for (int o = 1; o < T; o <<= 1){
    int v = (t >= o) ? sm[t - o] : 0;
    __syncthreads();
    sm[t] += v;
    __syncthreads();
  }
  int base = (t == 0) ? 0 : sm[t - 1];
  for (int i = lo; i < hi; ++i){
    int c = cnt[i];
    rowptr[i] = base;
    cursor[i] = base;
    base += c;
  }
  if (t == T - 1) rowptr[Mn] = tot;
}

// fill CSR neighbor slots: col[slot]=partner, es[slot]=(e<<1)|side
__global__ void k_fill(const int* __restrict__ src, const int* __restrict__ dst,
                       int* __restrict__ cursor, int* __restrict__ col,
                       int* __restrict__ es, int E){
  int i = blockIdx.x * blockDim.x + threadIdx.x;
  int stride = gridDim.x * blockDim.x;
  for (int e = i; e < E; e += stride){
    int s = src[e], t = dst[e];
    int ps = atomicAdd(&cursor[s], 1);
    col[ps] = t; es[ps] = (e << 1);
    int pt = atomicAdd(&cursor[t], 1);
    col[pt] = s; es[pt] = (e << 1) | 1;
  }
}

// edge-order sequential M build: M[e] = Rs[e]^T Rd[e]. Pure stream, no atomics.
__global__ void k_medge(const float* __restrict__ Rs, const float* __restrict__ Rd,
                        float* __restrict__ Mb, int E){
  int g  = blockIdx.x * blockDim.x + threadIdx.x;
  int wv = g >> 6, l = g & 63;
  int nw = (gridDim.x * blockDim.x) >> 6;
  int d1 = l >> 3, d2 = l & 7;
  for (int e = wv; e < E; e += nw){
    float rs = Rs[(size_t)e * 64 + l];
    float rd = Rd[(size_t)e * 64 + l];
    float Mm = 0.f;
    #pragma unroll
    for (int a = 0; a < 8; ++a)
      Mm += __shfl(rs, a * 8 + d1, 64) * __shfl(rd, a * 8 + d2, 64);
    Mb[(size_t)e * 64 + l] = Mm;
  }
}

// D build (gather side): wave per node in [v0,v1), lane l=(d1,d2).
__global__ void k_buildd(const float* __restrict__ Rs, const float* __restrict__ Rd,
                         const int* __restrict__ rowptr, const int* __restrict__ es,
                         float* __restrict__ Dd, int v0, int v1){
  int g = blockIdx.x * blockDim.x + threadIdx.x;
  int v = v0 + (g >> 6);
  if (v >= v1) return;
  int l = g & 63, d1 = l >> 3, d2 = l & 7;
  float Dacc = 0.f;
  int j0 = rowptr[v], j1 = rowptr[v + 1];
  int j = j0;
  for (; j + 2 <= j1; j += 2){
    int e0 = es[j], e1 = es[j + 1];
    const float* R0 = (e0 & 1) ? Rd : Rs;
    const float* R1 = (e1 & 1) ? Rd : Rs;
    float x0 = R0[(size_t)(e0 >> 1) * 64 + l];
    float x1 = R1[(size_t)(e1 >> 1) * 64 + l];
    #pragma unroll
    for (int a = 0; a < 8; ++a){
      float p0 = __shfl(x0, a * 8 + d1, 64);
      float s0 = __shfl(x0, a * 8 + d2, 64);
      float p1 = __shfl(x1, a * 8 + d1, 64);
      float s1 = __shfl(x1, a * 8 + d2, 64);
      Dacc += p0 * s0 + p1 * s1;
    }
  }
  for (; j < j1; ++j){
    int e0 = es[j];
    const float* R0 = (e0 & 1) ? Rd : Rs;
    float x0 = R0[(size_t)(e0 >> 1) * 64 + l];
    #pragma unroll
    for (int a = 0; a < 8; ++a)
      Dacc += __shfl(x0, a * 8 + d1, 64) * __shfl(x0, a * 8 + d2, 64);
  }
  Dd[(size_t)v * 64 + l] = ((d1 == d2) ? 1.f : 0.f) + LAM * Dacc;
}

// wave per node. Single-LDS-buffer + register-prefetch M-form matvec.
// Per chunk: write prefetched 8 p-rows + 8 M-rows (regs) to wave-private LDS,
// issue next chunk's gathers, compute 8 slots from LDS.
// LDS rows padded to 68 floats (272B, 16B-aligned) to kill write conflicts.
// No __syncthreads: each wave touches only its own LDS slice.
__global__ void k_mv(const float* __restrict__ Mb, const float* __restrict__ Dd,
                     const int* __restrict__ rowptr, const int* __restrict__ col,
                     const int* __restrict__ es, const float* __restrict__ p,
                     float* __restrict__ out, float* __restrict__ scal, int Mn){
  if (*(const int*)(scal + S_FLAG)) return;
  __shared__ float pbuf[4][8][68];
  __shared__ float mbuf[4][8][68];
  __shared__ int   cbuf[4][128];
  __shared__ int   ebuf[4][128];
  int g = blockIdx.x * blockDim.x + threadIdx.x;
  int v = g >> 6;
  if (v >= Mn) return;
  int w  = threadIdx.x >> 6;
  int l  = g & 63;
  int hi = l >> 3, lo = l & 7;
  int k8 = lo * 8;          // phase-A segment offset / phase-B row offset (dd*8)
  int b8 = hi * 8;          // phase-B batch offset
  int j0 = rowptr[v];
  int rowlen = rowptr[v + 1] - j0;

  // stage col/es for this wave's row (wave-synchronous LDS, no barrier needed)
  for (int jj = l; jj < rowlen && jj < 128; jj += 64){
    cbuf[w][jj] = col[j0 + jj];
    ebuf[w][jj] = es[j0 + jj];
  }

  int nch = (rowlen + 7) >> 3;

  auto gaddr = [&](int n, int& c, int& e){
    int jj = n * 8 + hi;
    c = v; e = 0;
    if (jj < rowlen){
      if (jj < 128){ c = cbuf[w][jj]; e = ebuf[w][jj] >> 1; }
      else         { c = col[j0 + jj]; e = es[j0 + jj] >> 1; }
    }
  };

  // acc = D_v p_v   (D row dd=lo; p row b=hi)
  const f4* pv4 = (const f4*)(p + (size_t)v * 64 + b8);
  f4 pv0 = pv4[0], pv1 = pv4[1];
  const f4* dr4 = (const f4*)(Dd + (size_t)v * 64 + k8);
  float acc = dot8v(dr4[0], dr4[1], pv0, pv1);

  f4 gp0, gp1, gm0, gm1;
  if (nch > 0){
    int c, e; gaddr(0, c, e);
    const float* pc = p + (size_t)c * 64 + k8;
    gp0 = *(const f4*)pc; gp1 = *(const f4*)(pc + 4);
    const float* mc = Mb + (size_t)e * 64 + k8;
    gm0 = *(const f4*)mc; gm1 = *(const f4*)(mc + 4);
  }

  for (int n = 0; n < nch; ++n){
    // commit prefetched chunk to LDS (in-order DS: after prior chunk's reads)
    float* dp = &pbuf[w][hi][k8];
    *(f4*)dp = gp0; *(f4*)(dp + 4) = gp1;
    float* dm = &mbuf[w][hi][k8];
    *(f4*)dm = gm0; *(f4*)(dm + 4) = gm1;
    // issue next chunk's gathers (latency hides under this chunk's compute)
    bool more = (n + 1 < nch);
    if (more){
      int c, e; gaddr(n + 1, c, e);
      const float* pc = p + (size_t)c * 64 + k8;
      gp0 = *(const f4*)pc; gp1 = *(const f4*)(pc + 4);
      const float* mc = Mb + (size_t)e * 64 + k8;
      gm0 = *(const f4*)mc; gm1 = *(const f4*)(mc + 4);
    }
    int jb = n * 8;
    int lim = rowlen - jb;
    if (lim >= 8){
      #pragma unroll
      for (int q = 0; q < 8; ++q){
        int jj = jb + q;                                       // wave-uniform
        int sd = ((jj < 128) ? ebuf[w][jj] : es[j0 + jj]) & 1;
        const float* pr = &pbuf[w][q][b8];
        f4 q0 = *(const f4*)pr, q1 = *(const f4*)(pr + 4);
        const float* mc = &mbuf[w][q][0];
        if (!sd){
          f4 m0 = *(const f4*)(mc + k8);
          f4 m1 = *(const f4*)(mc + k8 + 4);
          acc -= LAM * dot8v(m0, m1, q0, q1);
        } else {
          acc -= LAM * ( mc[lo]      * q0[0] + mc[lo +  8] * q0[1]
                       + mc[lo + 16] * q0[2] + mc[lo + 24] * q0[3]
                       + mc[lo + 32] * q1[0] + mc[lo + 40] * q1[1]
                       + mc[lo + 48] * q1[2] + mc[lo + 56] * q1[3]);
        }
      }
    } else {
      #pragma unroll
      for (int q = 0; q < 8; ++q){
        if (q < lim){
          int jj = jb + q;
          int sd = ((jj < 128) ? ebuf[w][jj] : es[j0 + jj]) & 1;
          const float* pr = &pbuf[w][q][b8];
          f4 q0 = *(const f4*)pr, q1 = *(const f4*)(pr + 4);
          const float* mc = &mbuf[w][q][0];
          if (!sd){
            f4 m0 = *(const f4*)(mc + k8);
            f4 m1 = *(const f4*)(mc + k8 + 4);
            acc -= LAM * dot8v(m0, m1, q0, q1);
          } else {
            acc -= LAM * ( mc[lo]      * q0[0] + mc[lo +  8] * q0[1]
                         + mc[lo + 16] * q0[2] + mc[lo + 24] * q0[3]
                         + mc[lo + 32] * q1[0] + mc[lo + 40] * q1[1]
                         + mc[lo + 48] * q1[2] + mc[lo + 56] * q1[3]);
          }
        }
      }
    }
  }
  out[(size_t)v * 64 + l] = acc;
  // fused p.Ap partial: p element at (v, hi*8+lo) from pv regs
  float pself = (lo & 4) ? ((lo & 2) ? ((lo & 1) ? pv1[3] : pv1[2])
                                     : ((lo & 1) ? pv1[1] : pv1[0]))
                         : ((lo & 2) ? ((lo & 1) ? pv0[3] : pv0[2])
                                     : ((lo & 1) ? pv0[1] : pv0[0]));
  float part = pself * acc;
  part += __shfl_xor(part, 1, 64);
  part += __shfl_xor(part, 2, 64);
  part += __shfl_xor(part, 4, 64);
  if (lo == 0)
    atomicAdd(&scal[S_PAP + hi * 256 + (blockIdx.x & 255)], part);
}

// c0 (batch-major) -> node-major buffer
__global__ void k_perm(const float* __restrict__ c0, float* __restrict__ xp, int Mn){
  int i = blockIdx.x * blockDim.x + threadIdx.x;
  int n4 = Mn * 16;
  if (i >= n4) return;
  int v = i >> 4, rem = i & 15, b = rem >> 1, half = rem & 1;
  f4 cv = *(const f4*)(c0 + ((size_t)b * Mn + v) * 8 + half * 4);
  ((f4*)xp)[i] = cv;
}

// r = c0p - Ap; p = r (in place over c0p); x (batch-major, d_out) = c0
__global__ void k_init_nm(float* __restrict__ p, const float* __restrict__ Ap,
                          float* __restrict__ r, float* __restrict__ x_bm,
                          float* __restrict__ scal, int n4tot, int Mn){
  int i = blockIdx.x * blockDim.x + threadIdx.x;
  int l = threadIdx.x & 63;
  float part = 0.f;
  if (i < n4tot){
    f4 cv = ((const f4*)p)[i];
    f4 av = ((const f4*)Ap)[i];
    f4 rv = cv - av;
    ((f4*)r)[i] = rv;
    ((f4*)p)[i] = rv;
    int v = i >> 4, rem = i & 15, b = rem >> 1, half = rem & 1;
    ((f4*)x_bm)[((size_t)b * Mn + v) * 2 + half] = cv;
    part = rv[0]*rv[0] + rv[1]*rv[1] + rv[2]*rv[2] + rv[3]*rv[3];
  }
  part += __shfl_xor(part, 1, 64);
  part += __shfl_xor(part, 16, 64);
  part += __shfl_xor(part, 32, 64);
  if ((l & 49) == 0)
    atomicAdd(&scal[S_RS + ((l >> 1) & 7) * 256 + (blockIdx.x & 255)], part);
}

// once: RSOLD[b] = sum(S_RS); zero both slot arrays
__global__ void k_s0(float* __restrict__ scal){
  __shared__ float sm[256];
  int t = threadIdx.x;
  int b = t >> 5, k0 = t & 31;
  float s = 0.f;
  #pragma unroll
  for (int i = 0; i < 8; ++i) s += scal[S_RS + b * 256 + k0 + i * 32];
  sm[t] = s;
  __syncthreads();
  if (t < 8){
    float tot = 0.f;
    #pragma unroll
    for (int i = 0; i < 32; ++i) tot += sm[t * 32 + i];
    scal[S_RSOLD + t] = tot;
  }
  __syncthreads();
  for (int i = t; i < 4096; i += 256) scal[S_PAP + i] = 0.f;
}

// x(batch-major) += a p; r -= a Ap; accumulate rnew.rnew
// alpha computed in-block from S_PAP slots (fused — no separate k_alpha launch)
__global__ void k_upd_nm(float* __restrict__ x_bm, float* __restrict__ r,
                         const float* __restrict__ p, const float* __restrict__ Ap,
                         float* __restrict__ scal, int n4tot, int Mn){
  if (*(const int*)(scal + S_FLAG)) return;
  __shared__ float sal[8];
  int t = threadIdx.x;
  if (t < 8){
    float s = 0.f;
    const float* pp = scal + S_PAP + t * 256;
    #pragma unroll 4
    for (int k = 0; k < 256; ++k) s += pp[k];
    sal[t] = scal[S_RSOLD + t] / (s + 1e-12f);
  }
  __syncthreads();
  int i = blockIdx.x * blockDim.x + t;
  int l = t & 63;
  float part = 0.f;
  if (i < n4tot){
    int v = i >> 4, rem = i & 15, b = rem >> 1, half = rem & 1;
    float al = sal[b];
    size_t xi = ((size_t)b * Mn + v) * 2 + half;
    f4 pv = ((const f4*)p)[i];
    f4 av = ((const f4*)Ap)[i];
    f4 xv = ((f4*)x_bm)[xi];
    f4 rv = ((f4*)r)[i];
    xv += al * pv;
    rv -= al * av;
    ((f4*)x_bm)[xi] = xv;
    ((f4*)r)[i] = rv;
    part = rv[0]*rv[0] + rv[1]*rv[1] + rv[2]*rv[2] + rv[3]*rv[3];
  }
  part += __shfl_xor(part, 1, 64);
  part += __shfl_xor(part, 16, 64);
  part += __shfl_xor(part, 32, 64);
  if ((l & 49) == 0)
    atomicAdd(&scal[S_RS + ((l >> 1) & 7) * 256 + (blockIdx.x & 255)], part);
}

// rsnew from S_RS; conv flag; BETA/RSOLD; zero slot arrays
__global__ void k_s2(float* __restrict__ scal){
  if (*(const int*)(scal + S_FLAG)) return;
  __shared__ float sm[256];
  __shared__ float rsn[8];
  int t = threadIdx.x;
  int b = t >> 5, k0 = t & 31;
  float s = 0.f;
  #pragma unroll
  for (int i = 0; i < 8; ++i) s += scal[S_RS + b * 256 + k0 + i * 32];
  sm[t] = s;
  __syncthreads();
  if (t < 8){
    float tot = 0.f;
    #pragma unroll
    for (int i = 0; i < 32; ++i) tot += sm[t * 32 + i];
    rsn[t] = tot;
  }
  __syncthreads();
  if (t == 0){
    float ssum = 0.f;
    for (int bb = 0; bb < 8; ++bb) ssum += rsn[bb];
    if (sqrtf(ssum / 8.0f) < TOL){
      *(int*)(scal + S_FLAG) = 1;   // freeze
    } else {
      for (int bb = 0; bb < 8; ++bb){
        scal[S_BETA + bb]  = rsn[bb] / (scal[S_RSOLD + bb] + 1e-12f);
        scal[S_RSOLD + bb] = rsn[bb];
      }
    }
  }
  __syncthreads();
  for (int i = t; i < 4096; i += 256) scal[S_PAP + i] = 0.f;
}

__global__ void k_pupd_nm(const float* __restrict__ r, float* __restrict__ p,
                          const float* __restrict__ scal, int n4tot){
  if (*(const int*)(scal + S_FLAG)) return;
  int i = blockIdx.x * blockDim.x + threadIdx.x;
  if (i >= n4tot) return;
  int b = (i >> 1) & 7;
  float be = scal[S_BETA + b];
  f4 rv = ((const f4*)r)[i];
  f4 pv = ((f4*)p)[i];
  pv = rv + be * pv;
  ((f4*)p)[i] = pv;
}

// ---------------- minimal fallback tier (batch-major, R-direct) ----------------
#define OS_RSOLD 0
#define OS_PAP   8
#define OS_RSNEW 16
#define OS_ALPHA 24
#define OS_BETA  32
#define OS_FLAG  40

__device__ __forceinline__ float blk_reduce_256(float v){
  __shared__ float sm[4];
  #pragma unroll
  for (int o = 32; o > 0; o >>= 1) v += __shfl_down(v, o, 64);
  int lane = threadIdx.x & 63, w = threadIdx.x >> 6;
  if (lane == 0) sm[w] = v;
  __syncthreads();
  return (threadIdx.x == 0) ? (sm[0] + sm[1] + sm[2] + sm[3]) : 0.f;
}

__global__ void k_setup_fb(float* scal){
  int i = blockIdx.x * blockDim.x + threadIdx.x;
  if (i < 64) scal[i] = 0.f;
}

__global__ void k_apinit(const float* __restrict__ in, float* __restrict__ out,
                         int n4tot, const int* __restrict__ flag){
  if (*flag) return;
  int j = blockIdx.x * blockDim.x + threadIdx.x;
  if (j < n4tot) ((f4*)out)[j] = ((const f4*)in)[j];
}

__global__ void k_mv_edge_fb(const float* __restrict__ Rs, const float* __restrict__ Rd,
                             const int* __restrict__ src, const int* __restrict__ dst,
                             const float* __restrict__ in, float* __restrict__ out,
                             int Mn, int E, const int* __restrict__ flag){
  if (*flag) return;
  int g  = blockIdx.x * blockDim.x + threadIdx.x;
  int wv = g >> 6, l = g & 63;
  int nw = (gridDim.x * blockDim.x) >> 6;
  int b = l >> 3, q = l & 7;
  for (int e = wv; e < E; e += nw){
    int s = src[e], t = dst[e];
    const f4* rs4 = (const f4*)(Rs + (size_t)e * 64 + q * 8);
    const f4* rd4 = (const f4*)(Rd + (size_t)e * 64 + q * 8);
    const f4* ps4 = (const f4*)(in + ((size_t)b * Mn + s) * 8);
    const f4* pd4 = (const f4*)(in + ((size_t)b * Mn + t) * 8);
    f4 ra0 = rs4[0], ra1 = rs4[1], pa0 = ps4[0], pa1 = ps4[1];
    f4 rb0 = rd4[0], rb1 = rd4[1], pb0 = pd4[0], pb1 = pd4[1];
    float re = dot8v(ra0, ra1, pa0, pa1) - dot8v(rb0, rb1, pb0, pb1);
    float cs = 0.f, cd = 0.f;
    #pragma unroll
    for (int a = 0; a < 8; ++a){
      float rea = __shfl(re, b * 8 + a, 64);
      cs += Rs[(size_t)e * 64 + a * 8 + q] * rea;
      cd += Rd[(size_t)e * 64 + a * 8 + q] * rea;
    }
    atomicAdd(&out[((size_t)b * Mn + s) * 8 + q],  LAM * cs);
    atomicAdd(&out[((size_t)b * Mn + t) * 8 + q], -LAM * cd);
  }
}

__global__ void k_init_o(const float* __restrict__ c0, const float* __restrict__ Ap,
                         float* __restrict__ x, float* __restrict__ r, float* __restrict__ p,
                         float* scal, int n4){
  int b = blockIdx.y;
  size_t base = (size_t)b * n4;
  int j = blockIdx.x * blockDim.x + threadIdx.x;
  float part = 0.f;
  if (j < n4){
    f4 cv = ((const f4*)c0)[base + j];
    f4 av = ((const f4*)Ap)[base + j];
    f4 rv = cv - av;
    ((f4*)x)[base + j] = cv;
    ((f4*)r)[base + j] = rv;
    ((f4*)p)[base + j] = rv;
    part = rv[0]*rv[0] + rv[1]*rv[1] + rv[2]*rv[2] + rv[3]*rv[3];
  }
  float tot = blk_reduce_256(part);
  if (threadIdx.x == 0) atomicAdd(&scal[OS_RSOLD + b], tot);
}

__global__ void k_dot_o(const float* __restrict__ p, const float* __restrict__ Ap,
                        float* scal, int n4){
  const int* flag = (const int*)(scal + OS_FLAG);
  if (*flag) return;
  int b = blockIdx.y;
  size_t base = (size_t)b * n4;
  int j = blockIdx.x * blockDim.x + threadIdx.x;
  float part = 0.f;
  if (j < n4){
    f4 pv = ((const f4*)p)[base + j];
    f4 av = ((const f4*)Ap)[base + j];
    part = pv[0]*av[0] + pv[1]*av[1] + pv[2]*av[2] + pv[3]*av[3];
  }
  float tot = blk_reduce_256(part);
  if (threadIdx.x == 0) atomicAdd(&scal[OS_PAP + b], tot);
}

__global__ void k_s1_o(float* scal){
  const int* flag = (const int*)(scal + OS_FLAG);
  if (*flag) return;
  int t = threadIdx.x;
  if (t < 8){
    scal[OS_ALPHA + t] = scal[OS_RSOLD + t] / (scal[OS_PAP + t] + 1e-12f);
    scal[OS_RSNEW + t] = 0.f;
  }
}

__global__ void k_upd_o(float* __restrict__ x, float* __restrict__ r,
                        const float* __restrict__ p, const float* __restrict__ Ap,
                        float* scal, int n4){
  const int* flag = (const int*)(scal + OS_FLAG);
  if (*flag) return;
  int b = blockIdx.y;
  size_t base = (size_t)b * n4;
  float al = scal[OS_ALPHA + b];
  int j = blockIdx.x * blockDim.x + threadIdx.x;
  float part = 0.f;
  if (j < n4){
    f4 pv = ((const f4*)p)[base + j];
    f4 av = ((const f4*)Ap)[base + j];
    f4 xv = ((f4*)x)[base + j];
    f4 rv = ((f4*)r)[base + j];
    xv += al * pv;
    rv -= al * av;
    ((f4*)x)[base + j] = xv;
    ((f4*)r)[base + j] = rv;
    part = rv[0]*rv[0] + rv[1]*rv[1] + rv[2]*rv[2] + rv[3]*rv[3];
  }
  float tot = blk_reduce_256(part);
  if (threadIdx.x == 0) atomicAdd(&scal[OS_RSNEW + b], tot);
}

__global__ void k_s2_o(float* scal){
  int* flag = (int*)(scal + OS_FLAG);
  if (*flag) return;
  if (threadIdx.x == 0){
    float ssum = 0.f;
    for (int bb = 0; bb < 8; ++bb) ssum += scal[OS_RSNEW + bb];
    if (sqrtf(ssum / 8.0f) < TOL){
      *flag = 1;
    } else {
      for (int bb = 0; bb < 8; ++bb){
        scal[OS_BETA + bb]  = scal[OS_RSNEW + bb] / (scal[OS_RSOLD + bb] + 1e-12f);
        scal[OS_RSOLD + bb] = scal[OS_RSNEW + bb];
        scal[OS_PAP + bb]   = 0.f;
      }
    }
  }
}

__global__ void k_pupd_o(const float* __restrict__ r, float* __restrict__ p,
                         float* scal, int n4){
  const int* flag = (const int*)(scal + OS_FLAG);
  if (*flag) return;
  int b = blockIdx.y;
  size_t base = (size_t)b * n4;
  float be = scal[OS_BETA + b];
  int j = blockIdx.x * blockDim.x + threadIdx.x;
  if (j < n4){
    f4 rv = ((const f4*)r)[base + j];
    f4 pv = ((f4*)p)[base + j];
    pv = rv + be * pv;
    ((f4*)p)[base + j] = pv;
  }
}

// ---------------- launch ----------------
extern "C" void kernel_launch(void* const* d_in, const int* in_sizes, int n_in,
                              void* d_out, int out_size, void* d_ws, size_t ws_size,
                              hipStream_t stream){
  const float* c0  = (const float*)d_in[0];
  const int*   src = (const int*)d_in[1];
  const int*   dst = (const int*)d_in[2];
  const float* Rs  = (const float*)d_in[3];
  const float* Rd  = (const float*)d_in[4];

  int N  = in_sizes[0];          // B*Mn*8 floats, B=8, d=8
  int Mn = N / 64;
  int E  = in_sizes[1];
  int n4tot = N / 4;
  int twoE = 2 * E;

  float* ws = (float*)d_ws;
  size_t off = 0;
  float* r    = ws + off;  off += N;
  float* p    = ws + off;  off += N;
  float* Ap   = ws + off;  off += N;
  float* scal = ws + off;  off += SCAL_F;
  float* Dd   = ws + off;  off += (size_t)Mn * 64;
  int* rowptr = (int*)(ws + off);  off += (size_t)((Mn + 1 + 3) & ~3);
  int* cursor = (int*)(ws + off);  off += (size_t)((Mn + 3) & ~3);
  int* colA   = (int*)(ws + off);  off += (size_t)twoE;
  int* esA    = (int*)(ws + off);  off += (size_t)twoE;
  float* Mb   = ws + off;  off += (size_t)E * 64;
  size_t need_main = off * 4;

  int nb_vec  = (n4tot + 255) / 256;
  int nb_node = (Mn * 64 + 255) / 256;

  if (ws_size >= need_main){
    k_setup_nm<<<512, 256, 0, stream>>>(scal, cursor, Mn);
    k_deg  <<<1024, 256, 0, stream>>>(src, dst, cursor, E);
    k_scan <<<1, 1024, 0, stream>>>(cursor, rowptr, cursor, Mn, twoE);
    k_fill <<<1024, 256, 0, stream>>>(src, dst, cursor, colA, esA, E);
    k_medge<<<4096, 256, 0, stream>>>(Rs, Rd, Mb, E);
    int Mh = (Mn + 1) / 2;
    int nb_h1 = (Mh * 64 + 255) / 256;
    int nb_h2 = ((Mn - Mh) * 64 + 255) / 256;
    k_buildd<<<nb_h1, 256, 0, stream>>>(Rs, Rd, rowptr, esA, Dd, 0, Mh);
    k_buildd<<<nb_h2, 256, 0, stream>>>(Rs, Rd, rowptr, esA, Dd, Mh, Mn);

    float* x_bm = (float*)d_out;
    k_perm<<<nb_vec, 256, 0, stream>>>(c0, p, Mn);   // p := c0 (node-major)
    k_mv<<<nb_node, 256, 0, stream>>>(Mb, Dd, rowptr, colA, esA, p, Ap, scal, Mn);
    k_init_nm<<<nb_vec, 256, 0, stream>>>(p, Ap, r, x_bm, scal, n4tot, Mn);
    k_s0<<<1, 256, 0, stream>>>(scal);

    for (int it = 0; it < NIT; ++it){
      k_mv<<<nb_node, 256, 0, stream>>>(Mb, Dd, rowptr, colA, esA, p, Ap, scal, Mn);
      k_upd_nm<<<nb_vec, 256, 0, stream>>>(x_bm, r, p, Ap, scal, n4tot, Mn);
      k_s2<<<1, 256, 0, stream>>>(scal);
      k_pupd_nm<<<nb_vec, 256, 0, stream>>>(r, p, scal, n4tot);
    }
  } else {
    // fallback: batch-major R-direct (needs 3N+64 floats)
    float* fr    = ws;
    float* fp    = fr + N;
    float* fAp   = fp + N;
    float* fscal = fAp + N;
    const int* flagp = (const int*)(fscal + OS_FLAG);
    int n4 = Mn * 2;
    dim3 vgrid((n4 + 255) / 256, 8);
    int cb = (n4tot + 255) / 256;
    float* x = (float*)d_out;

    k_setup_fb<<<1, 64, 0, stream>>>(fscal);
    k_apinit<<<cb, 256, 0, stream>>>(c0, fAp, n4tot, flagp);
    k_mv_edge_fb<<<2048, 256, 0, stream>>>(Rs, Rd, src, dst, c0, fAp, Mn, E, flagp);
    k_init_o<<<vgrid, 256, 0, stream>>>(c0, fAp, x, fr, fp, fscal, n4);
    for (int it = 0; it < NIT; ++it){
      k_apinit<<<cb, 256, 0, stream>>>(fp, fAp, n4tot, flagp);
      k_mv_edge_fb<<<2048, 256, 0, stream>>>(Rs, Rd, src, dst, fp, fAp, Mn, E, flagp);
      k_dot_o<<<vgrid, 256, 0, stream>>>(fp, fAp, fscal, n4);
      k_s1_o<<<1, 64, 0, stream>>>(fscal);
      k_upd_o<<<vgrid, 256, 0, stream>>>(x, fr, fp, fAp, fscal, n4);
      k_s2_o<<<1, 64, 0, stream>>>(fscal);
      k_pupd_o<<<vgrid, 256, 0, stream>>>(fr, fp, fscal, n4);
    }
  }
}